// Round 4
// baseline (196.093 us; speedup 1.0000x reference)
//
#include <hip/hip_runtime.h>
#include <math.h>

#define BN_EPS 1e-5f
#define ROWS 64

typedef __attribute__((ext_vector_type(8))) short short8;
typedef __attribute__((ext_vector_type(4))) float float4v;

__device__ __forceinline__ unsigned short f2bf(float f) {
    union { float f; unsigned int u; } v; v.f = f;
    unsigned int r = v.u + 0x7FFF + ((v.u >> 16) & 1);   // RNE
    return (unsigned short)(r >> 16);
}
__device__ __forceinline__ float softplus_f(float v) {
    float e = __expf(-fabsf(v));
    float r = __logf(1.f + e);
    return v > 0.f ? v + r : r;
}
__device__ __forceinline__ float swish_f(float a) {
    return a / (1.f + __expf(-a));
}

// in-place lane swaps (gfx950): a' = [a.lo32 | b.lo32], b' = [a.hi32 | b.hi32]
#define SWAP32(a, b) asm("v_permlane32_swap_b32 %0, %1" : "+v"(a), "+v"(b));
// within each 32-half: a' rows {a.r0, b.r0}, b' rows {a.r1, b.r1}
#define SWAP16(a, b) asm("v_permlane16_swap_b32 %0, %1" : "+v"(a), "+v"(b));

__device__ __forceinline__ float max16(const float* p) {
    float a = fmaxf(p[0], p[1]),  b = fmaxf(p[2], p[3]);
    float c = fmaxf(p[4], p[5]),  d = fmaxf(p[6], p[7]);
    float e = fmaxf(p[8], p[9]),  f = fmaxf(p[10], p[11]);
    float g = fmaxf(p[12], p[13]), h = fmaxf(p[14], p[15]);
    a = fmaxf(a, b); c = fmaxf(c, d); e = fmaxf(e, f); g = fmaxf(g, h);
    return fmaxf(fmaxf(a, c), fmaxf(e, g));
}
__device__ __forceinline__ float sum16(const float* p) {
    float a = p[0] + p[1],  b = p[2] + p[3];
    float c = p[4] + p[5],  d = p[6] + p[7];
    float e = p[8] + p[9],  f = p[10] + p[11];
    float g = p[12] + p[13], h = p[14] + p[15];
    a += b; c += d; e += f; g += h;
    return (a + c) + (e + g);
}

// ---- prep: WIDE elementwise (read-coalesced, write-scatter merged in L2) ----
#define PREP_WIDE_THREADS (1536 * 128 + 128 * 128)   // 212992 -> 832 blocks
__global__ void prep_weights(const float* __restrict__ W0, const float* __restrict__ W1,
                             const float* __restrict__ W2, const float* __restrict__ b0,
                             const float* __restrict__ b2,
                             const float* __restrict__ bn_scale, const float* __restrict__ bn_bias,
                             const float* __restrict__ bn_mean, const float* __restrict__ bn_var,
                             unsigned short* __restrict__ Wt0, unsigned short* __restrict__ Wt1,
                             unsigned short* __restrict__ Wt2, float* __restrict__ b0p,
                             float* __restrict__ b2p) {
    const int bid = blockIdx.x, tid = threadIdx.x;
    if (bid < 832) {
        int i = bid * 256 + tid;
        if (i < 1536 * 128) {
            int k = i / 1536, colp = i - k * 1536;
            int dd = colp / 48, j = colp - dd * 48;
            float v = (j < 47) ? W2[k * 1504 + dd * 47 + j] : 0.f;
            Wt2[(size_t)colp * 128 + k] = f2bf(v);
        } else {
            int i2 = i - 1536 * 128;
            int k = i2 >> 7, n = i2 & 127;
            Wt1[n * 128 + k] = f2bf(W1[k * 128 + n]);
        }
        return;
    }
    if (bid == 832) {
        __shared__ float lds[48 * 129 + 96];
        float* a   = lds + 48 * 129;
        float* bsh = a + 48;
        if (tid < 48) {
            float av = bn_scale[tid] * rsqrtf(bn_var[tid] + BN_EPS);
            a[tid] = av;
            bsh[tid] = bn_bias[tid] - bn_mean[tid] * av;
        }
        for (int idx = tid; idx < 48 * 128; idx += 256) {
            int k = idx >> 7, n = idx & 127;
            lds[k * 129 + n] = W0[k * 128 + n];
        }
        __syncthreads();
        #pragma unroll 4
        for (int it = 0; it < 32; ++it) {
            int n = (tid >> 6) + it * 4;
            int k = tid & 63;
            float v = (k < 48) ? lds[k * 129 + n] * a[k] : 0.f;
            Wt0[n * 64 + k] = f2bf(v);
        }
        if (tid < 128) {
            float s = b0[tid];
            #pragma unroll
            for (int k = 0; k < 48; ++k) s += bsh[k] * lds[k * 129 + tid];
            b0p[tid] = s;
        }
        return;
    }
    for (int e = tid; e < 32 * 48; e += 256) {
        int dd = e / 48, j = e - dd * 48;
        b2p[e] = (j < 47) ? b2[dd * 47 + j] : 0.f;
    }
}

// Round-3 lesson: the permlane TRANSP path pins ~16 extra values into ARCH VGPRs
// (inline-asm "+v"), and under __launch_bounds__(256,4) the 128-reg unified ceiling
// forces scratch spill (FETCH 121-220 MB across rounds 1-3) regardless of AGPR
// grouping. Measured occupancy was only ~3 blocks/CU anyway, so declare 3 waves/EU
// (~170-reg budget) — costs nothing, removes the spill pressure.
__launch_bounds__(256, 3)
__global__ void nsc_mfma(const float* __restrict__ x, const float* __restrict__ c,
                         const unsigned short* __restrict__ Wt0, const float* __restrict__ b0p,
                         const unsigned short* __restrict__ Wt1, const float* __restrict__ b1,
                         const unsigned short* __restrict__ Wt2, const float* __restrict__ b2p,
                         float* __restrict__ out, int N) {
    // region A [0,17408):       h0 [64][72] bf16  ->  h2 [64][136] bf16 (live through GEMM2)
    // region B [17408,34816):   h1 [64][136] bf16 (dead after phase 3; ldp [4][64] f32 aliases it)
    __shared__ __align__(16) char smem[34816];
    unsigned short* h0 = (unsigned short*)smem;            // stride 72
    unsigned short* h2 = (unsigned short*)smem;            // stride 136
    unsigned short* h1 = (unsigned short*)(smem + 17408);  // stride 136
    float*          ldp = (float*)(smem + 17408);          // [4][64], aliases dead h1

    const int tid  = threadIdx.x;
    const int lane = tid & 63;
    const int l    = lane & 15;
    const int q    = lane >> 4;
    const int wu   = __builtin_amdgcn_readfirstlane(tid >> 6);
    const int r0   = blockIdx.x * ROWS;

    // ---- phase 1: raw inputs -> h0 bf16 (BN folded into W0); xc passthrough ----
    for (int idx = tid; idx < 64 * 64; idx += 256) {
        int r = idx >> 6, j = idx & 63;
        float h = 0.f;
        if (j < 48) {
            int row = r0 + r;
            h = (j < 32) ? x[(size_t)row * 64 + 32 + j] : c[(size_t)row * 16 + (j - 32)];
        }
        h0[r * 72 + j] = f2bf(h);
    }
    for (int idx = tid; idx < 64 * 8; idx += 256) {
        int r = idx >> 3, ch = idx & 7;
        float4v v = *(const float4v*)(x + (size_t)(r0 + r) * 64 + 32 + ch * 4);
        *(float4v*)(out + (size_t)(r0 + r) * 64 + 32 + ch * 4) = v;
    }
    __syncthreads();

    // ---- phase 2: GEMM0  h1 = swish(h0 @ W0' + b0'), M=64 N=128 K=64(padded) ----
    {
        float4v acc[2][4];
        float4v z = {0.f, 0.f, 0.f, 0.f};
        #pragma unroll
        for (int nt = 0; nt < 2; ++nt)
            #pragma unroll
            for (int mt = 0; mt < 4; ++mt) acc[nt][mt] = z;
        #pragma unroll
        for (int ks = 0; ks < 2; ++ks) {
            short8 a[4];
            #pragma unroll
            for (int mt = 0; mt < 4; ++mt)
                a[mt] = *(const short8*)(h0 + (mt * 16 + l) * 72 + ks * 32 + (q << 3));
            #pragma unroll
            for (int nt = 0; nt < 2; ++nt) {
                int n0 = (wu * 2 + nt) * 16;
                short8 b = *(const short8*)(Wt0 + (n0 + l) * 64 + ks * 32 + (q << 3));
                #pragma unroll
                for (int mt = 0; mt < 4; ++mt)
                    acc[nt][mt] = __builtin_amdgcn_mfma_f32_16x16x32_bf16(a[mt], b, acc[nt][mt], 0, 0, 0);
            }
        }
        #pragma unroll
        for (int nt = 0; nt < 2; ++nt) {
            int n0 = (wu * 2 + nt) * 16;
            float bb = b0p[n0 + l];
            #pragma unroll
            for (int mt = 0; mt < 4; ++mt)
                #pragma unroll
                for (int r = 0; r < 4; ++r)
                    h1[(mt * 16 + q * 4 + r) * 136 + n0 + l] = f2bf(swish_f(acc[nt][mt][r] + bb));
        }
    }
    __syncthreads();

    // ---- phase 3: GEMM1  h2 = swish(h1 @ W1 + b1), M=64 N=128 K=128 ----
    {
        float4v acc[2][4];
        float4v z = {0.f, 0.f, 0.f, 0.f};
        #pragma unroll
        for (int nt = 0; nt < 2; ++nt)
            #pragma unroll
            for (int mt = 0; mt < 4; ++mt) acc[nt][mt] = z;
        #pragma unroll
        for (int ks = 0; ks < 4; ++ks) {
            short8 a[4];
            #pragma unroll
            for (int mt = 0; mt < 4; ++mt)
                a[mt] = *(const short8*)(h1 + (mt * 16 + l) * 136 + ks * 32 + (q << 3));
            #pragma unroll
            for (int nt = 0; nt < 2; ++nt) {
                int n0 = (wu * 2 + nt) * 16;
                short8 b = *(const short8*)(Wt1 + (n0 + l) * 128 + ks * 32 + (q << 3));
                #pragma unroll
                for (int mt = 0; mt < 4; ++mt)
                    acc[nt][mt] = __builtin_amdgcn_mfma_f32_16x16x32_bf16(a[mt], b, acc[nt][mt], 0, 0, 0);
            }
        }
        #pragma unroll
        for (int nt = 0; nt < 2; ++nt) {
            int n0 = (wu * 2 + nt) * 16;
            float bb = b1[n0 + l];
            #pragma unroll
            for (int mt = 0; mt < 4; ++mt)
                #pragma unroll
                for (int r = 0; r < 4; ++r)
                    h2[(mt * 16 + q * 4 + r) * 136 + n0 + l] = f2bf(swish_f(acc[nt][mt][r] + bb));
        }
    }
    __syncthreads();   // h1 dead; h2 live in region A

    // ---- phase 4: GEMM2 (swapped: p^T tiles) + 3-stage spline, all in-register ----
    // D-tile layout: lane (q,l), acc[jt][g][r] = p[row=16g+l][param=jt*16+4q+r].
    // 4x4 block transpose over (q-lanes x g-regs) via permlane swaps gives lane L
    // its own row's 16 params: pr[4j+r] = p[L][jt*16+4j+r]. No LDS round trip.
#define TRANSP(ACC, BJ, PR)                                                  \
    {                                                                        \
        _Pragma("unroll")                                                    \
        for (int r = 0; r < 4; ++r) {                                        \
            float a0 = ACC[0][r] + BJ[r];                                    \
            float a1 = ACC[1][r] + BJ[r];                                    \
            float a2 = ACC[2][r] + BJ[r];                                    \
            float a3 = ACC[3][r] + BJ[r];                                    \
            SWAP32(a0, a2) SWAP32(a1, a3)                                    \
            SWAP16(a0, a1) SWAP16(a2, a3)                                    \
            PR[r] = a0; PR[4 + r] = a1; PR[8 + r] = a2; PR[12 + r] = a3;     \
        }                                                                    \
    }

    float ld_local = 0.f;
    float yreg[8];
    for (int pass = 0; pass < 8; ++pass) {
        const int d = wu * 8 + pass;
        float t = x[(size_t)(r0 + lane) * 64 + d];   // issued early, consumed late
        // biases preloaded BEFORE the MFMA loop: L2 latency hides under MFMA,
        // and they're off the MFMA->VALU serial chain.
        float4v bj0 = *(const float4v*)(b2p + d * 48 +      (q << 2));
        float4v bj1 = *(const float4v*)(b2p + d * 48 + 16 + (q << 2));
        float4v bj2 = *(const float4v*)(b2p + d * 48 + 32 + (q << 2));
        bool inb = (t >= 0.f) && (t <= 1.f);
        float tc = fminf(fmaxf(t, 0.f), 1.f);

        float4v acc[3][4];
        float4v z = {0.f, 0.f, 0.f, 0.f};
        #pragma unroll
        for (int jt = 0; jt < 3; ++jt)
            #pragma unroll
            for (int smt = 0; smt < 4; ++smt) acc[jt][smt] = z;
        #pragma unroll
        for (int ks = 0; ks < 4; ++ks) {
            short8 bf[4];
            #pragma unroll
            for (int smt = 0; smt < 4; ++smt)
                bf[smt] = *(const short8*)(h2 + (smt * 16 + l) * 136 + ks * 32 + (q << 3));
            #pragma unroll
            for (int jt = 0; jt < 3; ++jt) {
                short8 a = *(const short8*)(Wt2 + (size_t)(d * 48 + jt * 16 + l) * 128 + ks * 32 + (q << 3));
                #pragma unroll
                for (int smt = 0; smt < 4; ++smt)
                    acc[jt][smt] = __builtin_amdgcn_mfma_f32_16x16x32_bf16(a, bf[smt], acc[jt][smt], 0, 0, 0);
            }
        }

        float pr[16];   // ONE array, reused W -> H -> D (liveness barrier)

        // ---- stage W: softmax (unnormalized) + bin search ----
        TRANSP(acc[0], bj0, pr)
        float mW = max16(pr);
        #pragma unroll
        for (int i = 0; i < 16; ++i) pr[i] = __expf(pr[i] - mW);
        float sW = sum16(pr);
        float ts = tc * sW;                  // search in unnormalized units
        float cum = 0.f, xkb = 0.f, dxb = pr[0];
        int idx = 0;
        #pragma unroll
        for (int i = 0; i < 16; ++i) {
            bool cnd = (ts >= cum);
            idx = cnd ? i : idx;
            xkb = cnd ? cum : xkb;
            dxb = cnd ? pr[i] : dxb;
            cum += pr[i];
        }

        // ---- stage H: softmax (unnormalized), extract ykb/dyb, then pr dies ----
        TRANSP(acc[1], bj1, pr)
        float mH = max16(pr);
        #pragma unroll
        for (int i = 0; i < 16; ++i) pr[i] = __expf(pr[i] - mH);
        float sH = sum16(pr);
        float invH = 1.f / sH;
        float ykb = ((((0 < idx ? pr[0] : 0.f) + (1 < idx ? pr[1] : 0.f)) +
                      ((2 < idx ? pr[2] : 0.f) + (3 < idx ? pr[3] : 0.f))) +
                     (((4 < idx ? pr[4] : 0.f) + (5 < idx ? pr[5] : 0.f)) +
                      ((6 < idx ? pr[6] : 0.f) + (7 < idx ? pr[7] : 0.f)))) +
                    ((((8 < idx ? pr[8] : 0.f) + (9 < idx ? pr[9] : 0.f)) +
                      ((10 < idx ? pr[10] : 0.f) + (11 < idx ? pr[11] : 0.f))) +
                     (((12 < idx ? pr[12] : 0.f) + (13 < idx ? pr[13] : 0.f)) +
                      ((14 < idx ? pr[14] : 0.f) + (15 < idx ? pr[15] : 0.f))));
        float dyb = pr[0];
        #pragma unroll
        for (int i = 1; i < 16; ++i) dyb = (i == idx) ? pr[i] : dyb;

        // ---- stage D: only 2 slope values per lane, then pr dies ----
        TRANSP(acc[2], bj2, pr)
        float pa0 = pr[0], pa1 = pr[0];
        #pragma unroll
        for (int i = 0; i < 16; ++i) {
            bool eq = (i == idx);
            pa0 = eq ? pr[(i > 0) ? (i - 1) : 0] : pa0;
            pa1 = eq ? pr[i] : pa1;
        }
        float d0 = (idx == 0)  ? 1.f : softplus_f(pa0);
        float d1 = (idx == 15) ? 1.f : softplus_f(pa1);

        float rdx = 1.f / dxb;
        float xi  = (ts - xkb) * rdx;        // == (tc - xkb_n)/dxb_n
        float dyn = dyb * invH;
        float ykn = ykb * invH;
        float s   = dyn * sW * rdx;          // (dyb/sH)/(dxb/sW)
        float xim = 1.f - xi;
        float x1m = xi * xim;
        float den = s + (d0 + d1 - 2.f * s) * x1m;
        float rden = 1.f / den;
        float y_in = ykn + dyn * (s * xi * xi + d0 * x1m) * rden;
        float dydx = s * s * (d1 * xi * xi + 2.f * s * x1m + d0 * xim * xim) * (rden * rden);

        yreg[pass] = inb ? y_in : t;
        ld_local += inb ? __logf(dydx) : 0.f;
    }

    // ---- epilogue: y from registers; log_det reduction ----
    {
        float4v* o = (float4v*)(out + (size_t)(r0 + lane) * 64 + wu * 8);
        o[0] = *(const float4v*)(yreg);
        o[1] = *(const float4v*)(yreg + 4);
    }
    ldp[wu * 64 + lane] = ld_local;
    __syncthreads();
    if (tid < 64) {
        out[(size_t)N * 64 + r0 + tid] =
            ldp[tid] + ldp[64 + tid] + ldp[128 + tid] + ldp[192 + tid];
    }
}

extern "C" void kernel_launch(void* const* d_in, const int* in_sizes, int n_in,
                              void* d_out, int out_size, void* d_ws, size_t ws_size,
                              hipStream_t stream) {
    const float* x        = (const float*)d_in[0];
    const float* c        = (const float*)d_in[1];
    const float* bn_scale = (const float*)d_in[2];
    const float* bn_bias  = (const float*)d_in[3];
    const float* bn_mean  = (const float*)d_in[4];
    const float* bn_var   = (const float*)d_in[5];
    const float* W0       = (const float*)d_in[6];
    const float* b0       = (const float*)d_in[7];
    const float* W1       = (const float*)d_in[8];
    const float* b1       = (const float*)d_in[9];
    const float* W2       = (const float*)d_in[10];
    const float* b2       = (const float*)d_in[11];
    float* out = (float*)d_out;

    unsigned short* Wt0 = (unsigned short*)d_ws;           // 128*64
    unsigned short* Wt1 = Wt0 + 128 * 64;                  // 128*128
    unsigned short* Wt2 = Wt1 + 128 * 128;                 // 1536*128
    float*          b2p = (float*)(Wt2 + 1536 * 128);      // 32*48
    float*          b0p = b2p + 32 * 48;                   // 128

    const int N = in_sizes[0] / 64;
    prep_weights<<<834, 256, 0, stream>>>(W0, W1, W2, b0, b2,
                                          bn_scale, bn_bias, bn_mean, bn_var,
                                          Wt0, Wt1, Wt2, b0p, b2p);
    nsc_mfma<<<N / ROWS, 256, 0, stream>>>(x, c, Wt0, b0p, Wt1, b1, Wt2, b2p, out, N);
}

// Round 5
// 164.679 us; speedup vs baseline: 1.1908x; 1.1908x over previous
//
#include <hip/hip_runtime.h>
#include <math.h>

#define BN_EPS 1e-5f
#define ROWS 64

typedef __attribute__((ext_vector_type(8))) short short8;
typedef __attribute__((ext_vector_type(4))) float float4v;

__device__ __forceinline__ unsigned short f2bf(float f) {
    union { float f; unsigned int u; } v; v.f = f;
    unsigned int r = v.u + 0x7FFF + ((v.u >> 16) & 1);   // RNE
    return (unsigned short)(r >> 16);
}
__device__ __forceinline__ float softplus_f(float v) {
    float e = __expf(-fabsf(v));
    float r = __logf(1.f + e);
    return v > 0.f ? v + r : r;
}
__device__ __forceinline__ float swish_f(float a) {
    return a / (1.f + __expf(-a));
}

__device__ __forceinline__ float max16(const float* p) {
    float a = fmaxf(p[0], p[1]),  b = fmaxf(p[2], p[3]);
    float c = fmaxf(p[4], p[5]),  d = fmaxf(p[6], p[7]);
    float e = fmaxf(p[8], p[9]),  f = fmaxf(p[10], p[11]);
    float g = fmaxf(p[12], p[13]), h = fmaxf(p[14], p[15]);
    a = fmaxf(a, b); c = fmaxf(c, d); e = fmaxf(e, f); g = fmaxf(g, h);
    return fmaxf(fmaxf(a, c), fmaxf(e, g));
}
__device__ __forceinline__ float sum16(const float* p) {
    float a = p[0] + p[1],  b = p[2] + p[3];
    float c = p[4] + p[5],  d = p[6] + p[7];
    float e = p[8] + p[9],  f = p[10] + p[11];
    float g = p[12] + p[13], h = p[14] + p[15];
    a += b; c += d; e += f; g += h;
    return (a + c) + (e + g);
}

// ---- prep: WIDE elementwise (read-coalesced, write-scatter merged in L2) ----
#define PREP_WIDE_THREADS (1536 * 128 + 128 * 128)   // 212992 -> 832 blocks
__global__ void prep_weights(const float* __restrict__ W0, const float* __restrict__ W1,
                             const float* __restrict__ W2, const float* __restrict__ b0,
                             const float* __restrict__ b2,
                             const float* __restrict__ bn_scale, const float* __restrict__ bn_bias,
                             const float* __restrict__ bn_mean, const float* __restrict__ bn_var,
                             unsigned short* __restrict__ Wt0, unsigned short* __restrict__ Wt1,
                             unsigned short* __restrict__ Wt2, float* __restrict__ b0p,
                             float* __restrict__ b2p) {
    const int bid = blockIdx.x, tid = threadIdx.x;
    if (bid < 832) {
        int i = bid * 256 + tid;
        if (i < 1536 * 128) {
            int k = i / 1536, colp = i - k * 1536;
            int dd = colp / 48, j = colp - dd * 48;
            float v = (j < 47) ? W2[k * 1504 + dd * 47 + j] : 0.f;
            Wt2[(size_t)colp * 128 + k] = f2bf(v);
        } else {
            int i2 = i - 1536 * 128;
            int k = i2 >> 7, n = i2 & 127;
            Wt1[n * 128 + k] = f2bf(W1[k * 128 + n]);
        }
        return;
    }
    if (bid == 832) {
        __shared__ float lds[48 * 129 + 96];
        float* a   = lds + 48 * 129;
        float* bsh = a + 48;
        if (tid < 48) {
            float av = bn_scale[tid] * rsqrtf(bn_var[tid] + BN_EPS);
            a[tid] = av;
            bsh[tid] = bn_bias[tid] - bn_mean[tid] * av;
        }
        for (int idx = tid; idx < 48 * 128; idx += 256) {
            int k = idx >> 7, n = idx & 127;
            lds[k * 129 + n] = W0[k * 128 + n];
        }
        __syncthreads();
        #pragma unroll 4
        for (int it = 0; it < 32; ++it) {
            int n = (tid >> 6) + it * 4;
            int k = tid & 63;
            float v = (k < 48) ? lds[k * 129 + n] * a[k] : 0.f;
            Wt0[n * 64 + k] = f2bf(v);
        }
        if (tid < 128) {
            float s = b0[tid];
            #pragma unroll
            for (int k = 0; k < 48; ++k) s += bsh[k] * lds[k * 129 + tid];
            b0p[tid] = s;
        }
        return;
    }
    for (int e = tid; e < 32 * 48; e += 256) {
        int dd = e / 48, j = e - dd * 48;
        b2p[e] = (j < 47) ? b2[dd * 47 + j] : 0.f;
    }
}

// Rounds 1-4 lesson: the permlane in-register transpose either spills (128-reg
// unified ceiling under (256,4)) or, with (256,3), balloons arch VGPRs and drops
// occupancy to 2 blocks/CU — net loss both ways. This kernel returns to the
// round-0 LDS pw round-trip (60 VGPR, no spill, ~3 blocks/CU) and instead fixes
// round-0's measured costs: (a) pw 8-way bank conflict via a 16B-slot XOR swizzle
// (slot c2 ^= ((row>>2)^(row>>4))&3 — enumerated: every bank pair hit exactly 2x
// = free), keeping ds_*_b128 alignment and the same LDS footprint; (b) tree
// max/sum + unnormalized bin search (numerics proven in rounds 2-4).
__launch_bounds__(256, 4)
__global__ void nsc_mfma(const float* __restrict__ x, const float* __restrict__ c,
                         const unsigned short* __restrict__ Wt0, const float* __restrict__ b0p,
                         const unsigned short* __restrict__ Wt1, const float* __restrict__ b1,
                         const unsigned short* __restrict__ Wt2, const float* __restrict__ b2p,
                         float* __restrict__ out, int N) {
    // region A [0,17408):       h0 [64][72] bf16  ->  h2 [64][136] bf16 (live through GEMM2)
    // region B [17408,38912):   h1 [64][136] bf16 ->  pw 4x[64][20] f32 (20480) + ldp [4][64] f32
    __shared__ __align__(16) char smem[38912];
    unsigned short* h0 = (unsigned short*)smem;            // stride 72
    unsigned short* h2 = (unsigned short*)smem;            // stride 136
    unsigned short* h1 = (unsigned short*)(smem + 17408);  // stride 136
    float*          ldp = (float*)(smem + 17408 + 20480);  // [4][64]

    const int tid  = threadIdx.x;
    const int lane = tid & 63;
    const int l    = lane & 15;
    const int q    = lane >> 4;
    const int wu   = __builtin_amdgcn_readfirstlane(tid >> 6);
    const int r0   = blockIdx.x * ROWS;
    float* pw = (float*)(smem + 17408) + wu * (64 * 20);   // per-wave staging, stride 20

    // pw swizzle fields (16B-slot XOR; row of a read = lane, row of a write = smt*16+l)
    const int s4  = (((lane >> 2) ^ (lane >> 4)) & 3) << 2;   // read-side: 4*swz(lane)
    const int qx4 = (((q ^ (l >> 2)) & 3) << 2);              // write-side: 4*(q ^ swz) before ^ (smt<<2)
    const int lw20 = l * 20;
    const int lane20 = lane * 20;

    // ---- phase 1: raw inputs -> h0 bf16 (BN folded into W0); xc passthrough ----
    for (int idx = tid; idx < 64 * 64; idx += 256) {
        int r = idx >> 6, j = idx & 63;
        float h = 0.f;
        if (j < 48) {
            int row = r0 + r;
            h = (j < 32) ? x[(size_t)row * 64 + 32 + j] : c[(size_t)row * 16 + (j - 32)];
        }
        h0[r * 72 + j] = f2bf(h);
    }
    for (int idx = tid; idx < 64 * 8; idx += 256) {
        int r = idx >> 3, ch = idx & 7;
        float4v v = *(const float4v*)(x + (size_t)(r0 + r) * 64 + 32 + ch * 4);
        *(float4v*)(out + (size_t)(r0 + r) * 64 + 32 + ch * 4) = v;
    }
    __syncthreads();

    // ---- phase 2: GEMM0  h1 = swish(h0 @ W0' + b0'), M=64 N=128 K=64(padded) ----
    {
        float4v acc[2][4];
        float4v z = {0.f, 0.f, 0.f, 0.f};
        #pragma unroll
        for (int nt = 0; nt < 2; ++nt)
            #pragma unroll
            for (int mt = 0; mt < 4; ++mt) acc[nt][mt] = z;
        #pragma unroll
        for (int ks = 0; ks < 2; ++ks) {
            short8 a[4];
            #pragma unroll
            for (int mt = 0; mt < 4; ++mt)
                a[mt] = *(const short8*)(h0 + (mt * 16 + l) * 72 + ks * 32 + (q << 3));
            #pragma unroll
            for (int nt = 0; nt < 2; ++nt) {
                int n0 = (wu * 2 + nt) * 16;
                short8 b = *(const short8*)(Wt0 + (n0 + l) * 64 + ks * 32 + (q << 3));
                #pragma unroll
                for (int mt = 0; mt < 4; ++mt)
                    acc[nt][mt] = __builtin_amdgcn_mfma_f32_16x16x32_bf16(a[mt], b, acc[nt][mt], 0, 0, 0);
            }
        }
        #pragma unroll
        for (int nt = 0; nt < 2; ++nt) {
            int n0 = (wu * 2 + nt) * 16;
            float bb = b0p[n0 + l];
            #pragma unroll
            for (int mt = 0; mt < 4; ++mt)
                #pragma unroll
                for (int r = 0; r < 4; ++r)
                    h1[(mt * 16 + q * 4 + r) * 136 + n0 + l] = f2bf(swish_f(acc[nt][mt][r] + bb));
        }
    }
    __syncthreads();

    // ---- phase 3: GEMM1  h2 = swish(h1 @ W1 + b1), M=64 N=128 K=128 ----
    {
        float4v acc[2][4];
        float4v z = {0.f, 0.f, 0.f, 0.f};
        #pragma unroll
        for (int nt = 0; nt < 2; ++nt)
            #pragma unroll
            for (int mt = 0; mt < 4; ++mt) acc[nt][mt] = z;
        #pragma unroll
        for (int ks = 0; ks < 4; ++ks) {
            short8 a[4];
            #pragma unroll
            for (int mt = 0; mt < 4; ++mt)
                a[mt] = *(const short8*)(h1 + (mt * 16 + l) * 136 + ks * 32 + (q << 3));
            #pragma unroll
            for (int nt = 0; nt < 2; ++nt) {
                int n0 = (wu * 2 + nt) * 16;
                short8 b = *(const short8*)(Wt1 + (n0 + l) * 128 + ks * 32 + (q << 3));
                #pragma unroll
                for (int mt = 0; mt < 4; ++mt)
                    acc[nt][mt] = __builtin_amdgcn_mfma_f32_16x16x32_bf16(a[mt], b, acc[nt][mt], 0, 0, 0);
            }
        }
        #pragma unroll
        for (int nt = 0; nt < 2; ++nt) {
            int n0 = (wu * 2 + nt) * 16;
            float bb = b1[n0 + l];
            #pragma unroll
            for (int mt = 0; mt < 4; ++mt)
                #pragma unroll
                for (int r = 0; r < 4; ++r)
                    h2[(mt * 16 + q * 4 + r) * 136 + n0 + l] = f2bf(swish_f(acc[nt][mt][r] + bb));
        }
    }
    __syncthreads();   // h1 dead -> pw reuses region B; h2 live in region A

    // ---- phase 4: GEMM2 (swapped: p^T tiles) + 3-stage spline ----
    // Round-0 register structure (60 VGPR, no spill under (256,4)). No asm fences:
    // pw is per-wave private, DS ops within a wave are in-order, compiler preserves
    // may-alias write->read order. pw addressing is XOR-swizzled on 16B slots.
    float ld_local = 0.f;
    float yreg[8];
    for (int pass = 0; pass < 8; ++pass) {
        const int d = wu * 8 + pass;
        float t = x[(size_t)(r0 + lane) * 64 + d];   // issued early, consumed after stage W
        bool inb = (t >= 0.f) && (t <= 1.f);
        float tc = fminf(fmaxf(t, 0.f), 1.f);

        float4v acc[3][4];
        float4v z = {0.f, 0.f, 0.f, 0.f};
        #pragma unroll
        for (int jt = 0; jt < 3; ++jt)
            #pragma unroll
            for (int smt = 0; smt < 4; ++smt) acc[jt][smt] = z;
        #pragma unroll
        for (int ks = 0; ks < 4; ++ks) {
            short8 bf[4];
            #pragma unroll
            for (int smt = 0; smt < 4; ++smt)
                bf[smt] = *(const short8*)(h2 + (smt * 16 + l) * 136 + ks * 32 + (q << 3));
            #pragma unroll
            for (int jt = 0; jt < 3; ++jt) {
                short8 a = *(const short8*)(Wt2 + (size_t)(d * 48 + jt * 16 + l) * 128 + ks * 32 + (q << 3));
                #pragma unroll
                for (int smt = 0; smt < 4; ++smt)
                    acc[jt][smt] = __builtin_amdgcn_mfma_f32_16x16x32_bf16(a, bf[smt], acc[jt][smt], 0, 0, 0);
            }
        }

        float pr[16];
        // ---- stage W (jt=0): softmax (unnormalized) + bin search ----
        {
            float4v bj = *(const float4v*)(b2p + d * 48 + (q << 2));
            #pragma unroll
            for (int smt = 0; smt < 4; ++smt)
                *(float4v*)(pw + smt * 320 + lw20 + (qx4 ^ (smt << 2))) = acc[0][smt] + bj;
            #pragma unroll
            for (int c2 = 0; c2 < 4; ++c2)
                *(float4v*)(pr + c2 * 4) = *(const float4v*)(pw + lane20 + ((c2 << 2) ^ s4));
        }
        float mW = max16(pr);
        #pragma unroll
        for (int i = 0; i < 16; ++i) pr[i] = __expf(pr[i] - mW);
        float sW = sum16(pr);
        float ts = tc * sW;                  // search in unnormalized units
        float cum = 0.f, xkb = 0.f, dxb = pr[0];
        int idx = 0;
        #pragma unroll
        for (int i = 0; i < 16; ++i) {
            bool cnd = (ts >= cum);
            idx = cnd ? i   : idx;
            xkb = cnd ? cum : xkb;
            dxb = cnd ? pr[i] : dxb;
            cum += pr[i];
        }

        // ---- stage H (jt=1): softmax (unnormalized), ykb/dyb ----
        {
            float4v bj = *(const float4v*)(b2p + d * 48 + 16 + (q << 2));
            #pragma unroll
            for (int smt = 0; smt < 4; ++smt)
                *(float4v*)(pw + smt * 320 + lw20 + (qx4 ^ (smt << 2))) = acc[1][smt] + bj;
            #pragma unroll
            for (int c2 = 0; c2 < 4; ++c2)
                *(float4v*)(pr + c2 * 4) = *(const float4v*)(pw + lane20 + ((c2 << 2) ^ s4));
        }
        float mH = max16(pr);
        #pragma unroll
        for (int i = 0; i < 16; ++i) pr[i] = __expf(pr[i] - mH);
        float sH = sum16(pr);
        float invH = 1.f / sH;
        float ykb = ((((0 < idx ? pr[0] : 0.f) + (1 < idx ? pr[1] : 0.f)) +
                      ((2 < idx ? pr[2] : 0.f) + (3 < idx ? pr[3] : 0.f))) +
                     (((4 < idx ? pr[4] : 0.f) + (5 < idx ? pr[5] : 0.f)) +
                      ((6 < idx ? pr[6] : 0.f) + (7 < idx ? pr[7] : 0.f)))) +
                    ((((8 < idx ? pr[8] : 0.f) + (9 < idx ? pr[9] : 0.f)) +
                      ((10 < idx ? pr[10] : 0.f) + (11 < idx ? pr[11] : 0.f))) +
                     (((12 < idx ? pr[12] : 0.f) + (13 < idx ? pr[13] : 0.f)) +
                      ((14 < idx ? pr[14] : 0.f) + (15 < idx ? pr[15] : 0.f))));
        float dyb = pr[0];
        #pragma unroll
        for (int i = 1; i < 16; ++i) dyb = (i == idx) ? pr[i] : dyb;

        // ---- stage D (jt=2): only 2 slope values needed per lane ----
        {
            float4v bj = *(const float4v*)(b2p + d * 48 + 32 + (q << 2));
            #pragma unroll
            for (int smt = 0; smt < 4; ++smt)
                *(float4v*)(pw + smt * 320 + lw20 + (qx4 ^ (smt << 2))) = acc[2][smt] + bj;
        }
        int i0 = (idx > 0)  ? idx - 1 : 0;
        int i1 = (idx < 15) ? idx     : 14;
        float pa0 = pw[lane20 + ((i0 & 12) ^ s4) + (i0 & 3)];
        float pa1 = pw[lane20 + ((i1 & 12) ^ s4) + (i1 & 3)];
        float d0 = (idx == 0)  ? 1.f : softplus_f(pa0);
        float d1 = (idx == 15) ? 1.f : softplus_f(pa1);

        float rdx = 1.f / dxb;
        float xi  = (ts - xkb) * rdx;        // == (tc - xkb_n)/dxb_n
        float dyn = dyb * invH;
        float ykn = ykb * invH;
        float s   = dyn * sW * rdx;          // (dyb/sH)/(dxb/sW)
        float xim = 1.f - xi;
        float x1m = xi * xim;
        float den = s + (d0 + d1 - 2.f * s) * x1m;
        float rden = 1.f / den;
        float y_in = ykn + dyn * (s * xi * xi + d0 * x1m) * rden;
        float dydx = s * s * (d1 * xi * xi + 2.f * s * x1m + d0 * xim * xim) * (rden * rden);

        yreg[pass] = inb ? y_in : t;
        ld_local += inb ? __logf(dydx) : 0.f;
    }

    // ---- epilogue: y from registers; log_det reduction ----
    {
        float4v* o = (float4v*)(out + (size_t)(r0 + lane) * 64 + wu * 8);
        o[0] = *(const float4v*)(yreg);
        o[1] = *(const float4v*)(yreg + 4);
    }
    ldp[wu * 64 + lane] = ld_local;
    __syncthreads();
    if (tid < 64) {
        out[(size_t)N * 64 + r0 + tid] =
            ldp[tid] + ldp[64 + tid] + ldp[128 + tid] + ldp[192 + tid];
    }
}

extern "C" void kernel_launch(void* const* d_in, const int* in_sizes, int n_in,
                              void* d_out, int out_size, void* d_ws, size_t ws_size,
                              hipStream_t stream) {
    const float* x        = (const float*)d_in[0];
    const float* c        = (const float*)d_in[1];
    const float* bn_scale = (const float*)d_in[2];
    const float* bn_bias  = (const float*)d_in[3];
    const float* bn_mean  = (const float*)d_in[4];
    const float* bn_var   = (const float*)d_in[5];
    const float* W0       = (const float*)d_in[6];
    const float* b0       = (const float*)d_in[7];
    const float* W1       = (const float*)d_in[8];
    const float* b1       = (const float*)d_in[9];
    const float* W2       = (const float*)d_in[10];
    const float* b2       = (const float*)d_in[11];
    float* out = (float*)d_out;

    unsigned short* Wt0 = (unsigned short*)d_ws;           // 128*64
    unsigned short* Wt1 = Wt0 + 128 * 64;                  // 128*128
    unsigned short* Wt2 = Wt1 + 128 * 128;                 // 1536*128
    float*          b2p = (float*)(Wt2 + 1536 * 128);      // 32*48
    float*          b0p = b2p + 32 * 48;                   // 128

    const int N = in_sizes[0] / 64;
    prep_weights<<<834, 256, 0, stream>>>(W0, W1, W2, b0, b2,
                                          bn_scale, bn_bias, bn_mean, bn_var,
                                          Wt0, Wt1, Wt2, b0p, b2p);
    nsc_mfma<<<N / ROWS, 256, 0, stream>>>(x, c, Wt0, b0p, Wt1, b1, Wt2, b2p, out, N);
}

// Round 6
// 161.668 us; speedup vs baseline: 1.2129x; 1.0186x over previous
//
#include <hip/hip_runtime.h>
#include <math.h>

#define BN_EPS 1e-5f
#define ROWS 64

typedef __attribute__((ext_vector_type(8))) short short8;
typedef __attribute__((ext_vector_type(4))) float float4v;

__device__ __forceinline__ unsigned short f2bf(float f) {
    union { float f; unsigned int u; } v; v.f = f;
    unsigned int r = v.u + 0x7FFF + ((v.u >> 16) & 1);   // RNE
    return (unsigned short)(r >> 16);
}
__device__ __forceinline__ float softplus_f(float v) {
    float e = __expf(-fabsf(v));
    float r = __logf(1.f + e);
    return v > 0.f ? v + r : r;
}
__device__ __forceinline__ float swish_f(float a) {
    return a / (1.f + __expf(-a));
}

__device__ __forceinline__ float max16(const float* p) {
    float a = fmaxf(p[0], p[1]),  b = fmaxf(p[2], p[3]);
    float c = fmaxf(p[4], p[5]),  d = fmaxf(p[6], p[7]);
    float e = fmaxf(p[8], p[9]),  f = fmaxf(p[10], p[11]);
    float g = fmaxf(p[12], p[13]), h = fmaxf(p[14], p[15]);
    a = fmaxf(a, b); c = fmaxf(c, d); e = fmaxf(e, f); g = fmaxf(g, h);
    return fmaxf(fmaxf(a, c), fmaxf(e, g));
}
__device__ __forceinline__ float sum16(const float* p) {
    float a = p[0] + p[1],  b = p[2] + p[3];
    float c = p[4] + p[5],  d = p[6] + p[7];
    float e = p[8] + p[9],  f = p[10] + p[11];
    float g = p[12] + p[13], h = p[14] + p[15];
    a += b; c += d; e += f; g += h;
    return (a + c) + (e + g);
}

// ---- prep: WIDE elementwise (read-coalesced, write-scatter merged in L2) ----
#define PREP_WIDE_THREADS (1536 * 128 + 128 * 128)   // 212992 -> 832 blocks
__global__ void prep_weights(const float* __restrict__ W0, const float* __restrict__ W1,
                             const float* __restrict__ W2, const float* __restrict__ b0,
                             const float* __restrict__ b2,
                             const float* __restrict__ bn_scale, const float* __restrict__ bn_bias,
                             const float* __restrict__ bn_mean, const float* __restrict__ bn_var,
                             unsigned short* __restrict__ Wt0, unsigned short* __restrict__ Wt1,
                             unsigned short* __restrict__ Wt2, float* __restrict__ b0p,
                             float* __restrict__ b2p) {
    const int bid = blockIdx.x, tid = threadIdx.x;
    if (bid < 832) {
        int i = bid * 256 + tid;
        if (i < 1536 * 128) {
            int k = i / 1536, colp = i - k * 1536;
            int dd = colp / 48, j = colp - dd * 48;
            float v = (j < 47) ? W2[k * 1504 + dd * 47 + j] : 0.f;
            Wt2[(size_t)colp * 128 + k] = f2bf(v);
        } else {
            int i2 = i - 1536 * 128;
            int k = i2 >> 7, n = i2 & 127;
            Wt1[n * 128 + k] = f2bf(W1[k * 128 + n]);
        }
        return;
    }
    if (bid == 832) {
        __shared__ float lds[48 * 129 + 96];
        float* a   = lds + 48 * 129;
        float* bsh = a + 48;
        if (tid < 48) {
            float av = bn_scale[tid] * rsqrtf(bn_var[tid] + BN_EPS);
            a[tid] = av;
            bsh[tid] = bn_bias[tid] - bn_mean[tid] * av;
        }
        for (int idx = tid; idx < 48 * 128; idx += 256) {
            int k = idx >> 7, n = idx & 127;
            lds[k * 129 + n] = W0[k * 128 + n];
        }
        __syncthreads();
        #pragma unroll 4
        for (int it = 0; it < 32; ++it) {
            int n = (tid >> 6) + it * 4;
            int k = tid & 63;
            float v = (k < 48) ? lds[k * 129 + n] * a[k] : 0.f;
            Wt0[n * 64 + k] = f2bf(v);
        }
        if (tid < 128) {
            float s = b0[tid];
            #pragma unroll
            for (int k = 0; k < 48; ++k) s += bsh[k] * lds[k * 129 + tid];
            b0p[tid] = s;
        }
        return;
    }
    for (int e = tid; e < 32 * 48; e += 256) {
        int dd = e / 48, j = e - dd * 48;
        b2p[e] = (j < 47) ? b2[dd * 47 + j] : 0.f;
    }
}

// Round-5 lesson (octet model): stride-20 pw is ALREADY conflict-free for b128
// ops when the HW processes lanes in consecutive octets (20L mod 32 distinct for
// L=0..7, since gcd(20,32)=4 and 5 coprime 8). The round-5 XOR swizzle broke the
// octet disjointness and ADDED conflicts (2.8M -> 7.0M, 89 -> 103 us). This kernel
// is round-0's exact memory structure + the proven-numerics serial-chain
// shorteners from rounds 2-5 (tree max/sum, unnormalized bin search, tree ykb).
__launch_bounds__(256, 4)
__global__ void nsc_mfma(const float* __restrict__ x, const float* __restrict__ c,
                         const unsigned short* __restrict__ Wt0, const float* __restrict__ b0p,
                         const unsigned short* __restrict__ Wt1, const float* __restrict__ b1,
                         const unsigned short* __restrict__ Wt2, const float* __restrict__ b2p,
                         float* __restrict__ out, int N) {
    // region A [0,17408):       h0 [64][72] bf16  ->  h2 [64][136] bf16 (live through GEMM2)
    // region B [17408,38912):   h1 [64][136] bf16 ->  pw 4x[64][20] f32 (20480) + ldp [4][64] f32
    __shared__ __align__(16) char smem[38912];
    unsigned short* h0 = (unsigned short*)smem;            // stride 72
    unsigned short* h2 = (unsigned short*)smem;            // stride 136
    unsigned short* h1 = (unsigned short*)(smem + 17408);  // stride 136
    float*          ldp = (float*)(smem + 17408 + 20480);  // [4][64]

    const int tid  = threadIdx.x;
    const int lane = tid & 63;
    const int l    = lane & 15;
    const int q    = lane >> 4;
    const int wu   = __builtin_amdgcn_readfirstlane(tid >> 6);
    const int r0   = blockIdx.x * ROWS;
    float* pw = (float*)(smem + 17408) + wu * (64 * 20);   // per-wave staging, stride 20

    // ---- phase 1: raw inputs -> h0 bf16 (BN folded into W0); xc passthrough ----
    for (int idx = tid; idx < 64 * 64; idx += 256) {
        int r = idx >> 6, j = idx & 63;
        float h = 0.f;
        if (j < 48) {
            int row = r0 + r;
            h = (j < 32) ? x[(size_t)row * 64 + 32 + j] : c[(size_t)row * 16 + (j - 32)];
        }
        h0[r * 72 + j] = f2bf(h);
    }
    for (int idx = tid; idx < 64 * 8; idx += 256) {
        int r = idx >> 3, ch = idx & 7;
        float4v v = *(const float4v*)(x + (size_t)(r0 + r) * 64 + 32 + ch * 4);
        *(float4v*)(out + (size_t)(r0 + r) * 64 + 32 + ch * 4) = v;
    }
    __syncthreads();

    // ---- phase 2: GEMM0  h1 = swish(h0 @ W0' + b0'), M=64 N=128 K=64(padded) ----
    {
        float4v acc[2][4];
        float4v z = {0.f, 0.f, 0.f, 0.f};
        #pragma unroll
        for (int nt = 0; nt < 2; ++nt)
            #pragma unroll
            for (int mt = 0; mt < 4; ++mt) acc[nt][mt] = z;
        #pragma unroll
        for (int ks = 0; ks < 2; ++ks) {
            short8 a[4];
            #pragma unroll
            for (int mt = 0; mt < 4; ++mt)
                a[mt] = *(const short8*)(h0 + (mt * 16 + l) * 72 + ks * 32 + (q << 3));
            #pragma unroll
            for (int nt = 0; nt < 2; ++nt) {
                int n0 = (wu * 2 + nt) * 16;
                short8 b = *(const short8*)(Wt0 + (n0 + l) * 64 + ks * 32 + (q << 3));
                #pragma unroll
                for (int mt = 0; mt < 4; ++mt)
                    acc[nt][mt] = __builtin_amdgcn_mfma_f32_16x16x32_bf16(a[mt], b, acc[nt][mt], 0, 0, 0);
            }
        }
        #pragma unroll
        for (int nt = 0; nt < 2; ++nt) {
            int n0 = (wu * 2 + nt) * 16;
            float bb = b0p[n0 + l];
            #pragma unroll
            for (int mt = 0; mt < 4; ++mt)
                #pragma unroll
                for (int r = 0; r < 4; ++r)
                    h1[(mt * 16 + q * 4 + r) * 136 + n0 + l] = f2bf(swish_f(acc[nt][mt][r] + bb));
        }
    }
    __syncthreads();

    // ---- phase 3: GEMM1  h2 = swish(h1 @ W1 + b1), M=64 N=128 K=128 ----
    {
        float4v acc[2][4];
        float4v z = {0.f, 0.f, 0.f, 0.f};
        #pragma unroll
        for (int nt = 0; nt < 2; ++nt)
            #pragma unroll
            for (int mt = 0; mt < 4; ++mt) acc[nt][mt] = z;
        #pragma unroll
        for (int ks = 0; ks < 4; ++ks) {
            short8 a[4];
            #pragma unroll
            for (int mt = 0; mt < 4; ++mt)
                a[mt] = *(const short8*)(h1 + (mt * 16 + l) * 136 + ks * 32 + (q << 3));
            #pragma unroll
            for (int nt = 0; nt < 2; ++nt) {
                int n0 = (wu * 2 + nt) * 16;
                short8 b = *(const short8*)(Wt1 + (n0 + l) * 128 + ks * 32 + (q << 3));
                #pragma unroll
                for (int mt = 0; mt < 4; ++mt)
                    acc[nt][mt] = __builtin_amdgcn_mfma_f32_16x16x32_bf16(a[mt], b, acc[nt][mt], 0, 0, 0);
            }
        }
        #pragma unroll
        for (int nt = 0; nt < 2; ++nt) {
            int n0 = (wu * 2 + nt) * 16;
            float bb = b1[n0 + l];
            #pragma unroll
            for (int mt = 0; mt < 4; ++mt)
                #pragma unroll
                for (int r = 0; r < 4; ++r)
                    h2[(mt * 16 + q * 4 + r) * 136 + n0 + l] = f2bf(swish_f(acc[nt][mt][r] + bb));
        }
    }
    __syncthreads();   // h1 dead -> pw reuses region B; h2 live in region A

    // ---- phase 4: GEMM2 (swapped: p^T tiles) + 3-stage spline ----
    // Round-0 register structure (60 VGPR, no spill under (256,4)). No asm fences:
    // pw is per-wave private, DS ops within a wave are in-order, compiler preserves
    // may-alias write->read order.
    float ld_local = 0.f;
    float yreg[8];
    for (int pass = 0; pass < 8; ++pass) {
        const int d = wu * 8 + pass;
        float t = x[(size_t)(r0 + lane) * 64 + d];   // issued early, consumed after stage W
        bool inb = (t >= 0.f) && (t <= 1.f);
        float tc = fminf(fmaxf(t, 0.f), 1.f);

        float4v acc[3][4];
        float4v z = {0.f, 0.f, 0.f, 0.f};
        #pragma unroll
        for (int jt = 0; jt < 3; ++jt)
            #pragma unroll
            for (int smt = 0; smt < 4; ++smt) acc[jt][smt] = z;
        #pragma unroll
        for (int ks = 0; ks < 4; ++ks) {
            short8 bf[4];
            #pragma unroll
            for (int smt = 0; smt < 4; ++smt)
                bf[smt] = *(const short8*)(h2 + (smt * 16 + l) * 136 + ks * 32 + (q << 3));
            #pragma unroll
            for (int jt = 0; jt < 3; ++jt) {
                short8 a = *(const short8*)(Wt2 + (size_t)(d * 48 + jt * 16 + l) * 128 + ks * 32 + (q << 3));
                #pragma unroll
                for (int smt = 0; smt < 4; ++smt)
                    acc[jt][smt] = __builtin_amdgcn_mfma_f32_16x16x32_bf16(a, bf[smt], acc[jt][smt], 0, 0, 0);
            }
        }

        float pr[16];
        // ---- stage W (jt=0): softmax (unnormalized) + bin search ----
        {
            float4v bj = *(const float4v*)(b2p + d * 48 + (q << 2));
            #pragma unroll
            for (int smt = 0; smt < 4; ++smt)
                *(float4v*)(pw + (smt * 16 + l) * 20 + (q << 2)) = acc[0][smt] + bj;
            #pragma unroll
            for (int c2 = 0; c2 < 4; ++c2)
                *(float4v*)(pr + c2 * 4) = *(const float4v*)(pw + lane * 20 + c2 * 4);
        }
        float mW = max16(pr);
        #pragma unroll
        for (int i = 0; i < 16; ++i) pr[i] = __expf(pr[i] - mW);
        float sW = sum16(pr);
        float ts = tc * sW;                  // search in unnormalized units
        float cum = 0.f, xkb = 0.f, dxb = pr[0];
        int idx = 0;
        #pragma unroll
        for (int i = 0; i < 16; ++i) {
            bool cnd = (ts >= cum);
            idx = cnd ? i   : idx;
            xkb = cnd ? cum : xkb;
            dxb = cnd ? pr[i] : dxb;
            cum += pr[i];
        }

        // ---- stage H (jt=1): softmax (unnormalized), ykb/dyb ----
        {
            float4v bj = *(const float4v*)(b2p + d * 48 + 16 + (q << 2));
            #pragma unroll
            for (int smt = 0; smt < 4; ++smt)
                *(float4v*)(pw + (smt * 16 + l) * 20 + (q << 2)) = acc[1][smt] + bj;
            #pragma unroll
            for (int c2 = 0; c2 < 4; ++c2)
                *(float4v*)(pr + c2 * 4) = *(const float4v*)(pw + lane * 20 + c2 * 4);
        }
        float mH = max16(pr);
        #pragma unroll
        for (int i = 0; i < 16; ++i) pr[i] = __expf(pr[i] - mH);
        float sH = sum16(pr);
        float invH = 1.f / sH;
        float ykb = ((((0 < idx ? pr[0] : 0.f) + (1 < idx ? pr[1] : 0.f)) +
                      ((2 < idx ? pr[2] : 0.f) + (3 < idx ? pr[3] : 0.f))) +
                     (((4 < idx ? pr[4] : 0.f) + (5 < idx ? pr[5] : 0.f)) +
                      ((6 < idx ? pr[6] : 0.f) + (7 < idx ? pr[7] : 0.f)))) +
                    ((((8 < idx ? pr[8] : 0.f) + (9 < idx ? pr[9] : 0.f)) +
                      ((10 < idx ? pr[10] : 0.f) + (11 < idx ? pr[11] : 0.f))) +
                     (((12 < idx ? pr[12] : 0.f) + (13 < idx ? pr[13] : 0.f)) +
                      ((14 < idx ? pr[14] : 0.f) + (15 < idx ? pr[15] : 0.f))));
        float dyb = pr[0];
        #pragma unroll
        for (int i = 1; i < 16; ++i) dyb = (i == idx) ? pr[i] : dyb;

        // ---- stage D (jt=2): only 2 slope values needed per lane ----
        {
            float4v bj = *(const float4v*)(b2p + d * 48 + 32 + (q << 2));
            #pragma unroll
            for (int smt = 0; smt < 4; ++smt)
                *(float4v*)(pw + (smt * 16 + l) * 20 + (q << 2)) = acc[2][smt] + bj;
        }
        int i0 = (idx > 0)  ? idx - 1 : 0;
        int i1 = (idx < 15) ? idx     : 14;
        float pa0 = pw[lane * 20 + i0];
        float pa1 = pw[lane * 20 + i1];
        float d0 = (idx == 0)  ? 1.f : softplus_f(pa0);
        float d1 = (idx == 15) ? 1.f : softplus_f(pa1);

        float rdx = 1.f / dxb;
        float xi  = (ts - xkb) * rdx;        // == (tc - xkb_n)/dxb_n
        float dyn = dyb * invH;
        float ykn = ykb * invH;
        float s   = dyn * sW * rdx;          // (dyb/sH)/(dxb/sW)
        float xim = 1.f - xi;
        float x1m = xi * xim;
        float den = s + (d0 + d1 - 2.f * s) * x1m;
        float rden = 1.f / den;
        float y_in = ykn + dyn * (s * xi * xi + d0 * x1m) * rden;
        float dydx = s * s * (d1 * xi * xi + 2.f * s * x1m + d0 * xim * xim) * (rden * rden);

        yreg[pass] = inb ? y_in : t;
        ld_local += inb ? __logf(dydx) : 0.f;
    }

    // ---- epilogue: y from registers; log_det reduction ----
    {
        float4v* o = (float4v*)(out + (size_t)(r0 + lane) * 64 + wu * 8);
        o[0] = *(const float4v*)(yreg);
        o[1] = *(const float4v*)(yreg + 4);
    }
    ldp[wu * 64 + lane] = ld_local;
    __syncthreads();
    if (tid < 64) {
        out[(size_t)N * 64 + r0 + tid] =
            ldp[tid] + ldp[64 + tid] + ldp[128 + tid] + ldp[192 + tid];
    }
}

extern "C" void kernel_launch(void* const* d_in, const int* in_sizes, int n_in,
                              void* d_out, int out_size, void* d_ws, size_t ws_size,
                              hipStream_t stream) {
    const float* x        = (const float*)d_in[0];
    const float* c        = (const float*)d_in[1];
    const float* bn_scale = (const float*)d_in[2];
    const float* bn_bias  = (const float*)d_in[3];
    const float* bn_mean  = (const float*)d_in[4];
    const float* bn_var   = (const float*)d_in[5];
    const float* W0       = (const float*)d_in[6];
    const float* b0       = (const float*)d_in[7];
    const float* W1       = (const float*)d_in[8];
    const float* b1       = (const float*)d_in[9];
    const float* W2       = (const float*)d_in[10];
    const float* b2       = (const float*)d_in[11];
    float* out = (float*)d_out;

    unsigned short* Wt0 = (unsigned short*)d_ws;           // 128*64
    unsigned short* Wt1 = Wt0 + 128 * 64;                  // 128*128
    unsigned short* Wt2 = Wt1 + 128 * 128;                 // 1536*128
    float*          b2p = (float*)(Wt2 + 1536 * 128);      // 32*48
    float*          b0p = b2p + 32 * 48;                   // 128

    const int N = in_sizes[0] / 64;
    prep_weights<<<834, 256, 0, stream>>>(W0, W1, W2, b0, b2,
                                          bn_scale, bn_bias, bn_mean, bn_var,
                                          Wt0, Wt1, Wt2, b0p, b2p);
    nsc_mfma<<<N / ROWS, 256, 0, stream>>>(x, c, Wt0, b0p, Wt1, b1, Wt2, b2p, out, N);
}